// Round 2
// baseline (363.462 us; speedup 1.0000x reference)
//
#include <hip/hip_runtime.h>
#include <hip/hip_bf16.h>

// mp: [1, 21, 16, 256, 256] fp32
#define CC   21
#define DD   16
#define HH   256
#define WW   256
#define HWP  (HH * WW)      // 65536
#define DHW  (DD * HWP)     // 1048576

// Tile: full D=16, H-tile 2, W-tile 32 => 1024 px per block, 256 thr, 4 px/thr
#define TW 32
#define TH 2
#define DP 20               // D + 4
#define HP 6                // TH + 4
#define WP 36               // TW + 4
#define A_SZ (DP * HP * WP) // 4320 raw padded
#define B_SZ (DP * HP * TW) // 3840 W-blurred

// Fused: separable 5^3 box blur (replicate pad) for sum-image + 21 channels,
// streaming weighted-median selection in registers, single global write.
// The 1/125 kernel scale cancels under normalization and is dropped;
// total = sum_c blur(mp_c) = blur(sum_c mp) by linearity (one extra image).
__global__ __launch_bounds__(256) void fused_kernel(const float* __restrict__ mp,
                                                    float* __restrict__ out) {
    __shared__ float A[A_SZ];
    __shared__ float B[B_SZ];

    const int w0 = blockIdx.x * TW;
    const int h0 = blockIdx.y * TH;
    const int tid = threadIdx.x;
    const int x  = tid & 31;
    const int y  = (tid >> 5) & 1;
    const int dg = tid >> 6;          // 0..3, 4 d-outputs each
    const int d0 = dg * 4;

    // per-pixel streaming median state (4 pixels along D per thread)
    float inv[4], s[4], val0[4], val1[4];
    int med0[4], med1[4];

    for (int img = 0; img <= CC; ++img) {
        // ---- stage padded raw tile into A (img 0: channel-sum image) ----
        if (img == 0) {
            for (int i = tid; i < A_SZ; i += 256) {
                int dz  = i / (HP * WP);
                int rem = i - dz * (HP * WP);
                int py  = rem / WP;
                int px  = rem - py * WP;
                int d = min(DD - 1, max(0, dz - 2));
                int h = min(HH - 1, max(0, h0 + py - 2));
                int w = min(WW - 1, max(0, w0 + px - 2));
                const float* p = mp + (d * HWP + h * WW + w);
                float sum = 0.f;
                #pragma unroll
                for (int c = 0; c < CC; ++c) sum += p[(size_t)c * DHW];
                A[i] = sum;
            }
        } else {
            const float* src = mp + (size_t)(img - 1) * DHW;
            for (int i = tid; i < A_SZ; i += 256) {
                int dz  = i / (HP * WP);
                int rem = i - dz * (HP * WP);
                int py  = rem / WP;
                int px  = rem - py * WP;
                int d = min(DD - 1, max(0, dz - 2));
                int h = min(HH - 1, max(0, h0 + py - 2));
                int w = min(WW - 1, max(0, w0 + px - 2));
                A[i] = src[d * HWP + h * WW + w];
            }
        }
        // covers: stage->Wpass on A, AND prev HD-reads(B)->Wpass-writes(B)
        __syncthreads();

        // ---- W pass: B[dz][py][x] = sum_{j<5} A[dz][py][x+j] ----
        for (int i = tid; i < B_SZ; i += 256) {
            int bx  = i & 31;
            int row = i >> 5;                 // dz*HP + py
            const float* a = &A[row * WP + bx];
            B[i] = a[0] + a[1] + a[2] + a[3] + a[4];
        }
        __syncthreads();

        // ---- fused H+D pass in registers ----
        float wv[8];
        #pragma unroll
        for (int k = 0; k < 8; ++k) {
            const float* b = &B[((d0 + k) * HP + y) * TW + x];
            wv[k] = b[0] + b[TW] + b[2 * TW] + b[3 * TW] + b[4 * TW];
        }
        if (img == 0) {
            #pragma unroll
            for (int p = 0; p < 4; ++p) {
                float r = wv[p] + wv[p + 1] + wv[p + 2] + wv[p + 3] + wv[p + 4];
                inv[p] = 1.0f / r;
                s[p] = 0.f; med0[p] = 0; med1[p] = 0; val0[p] = 0.f; val1[p] = 0.f;
            }
        } else {
            const int c = img - 1;
            #pragma unroll
            for (int p = 0; p < 4; ++p) {
                float r  = wv[p] + wv[p + 1] + wv[p + 2] + wv[p + 3] + wv[p + 4];
                float yn = r * inv[p];
                float sn = s[p] + yn;
                if (c == 0) { val0[p] = yn; val1[p] = yn; }       // defaults (med=0)
                if (yn > 0.f && sn < 0.5f) { med0[p] = c; val0[p] = yn; }  // last qualifying
                if (med1[p] == 0 && c > 0 && sn > 0.5f) { med1[p] = c; val1[p] = yn; } // first qualifying
                s[p] = sn;
            }
        }
    }

    // ---- write out: keep med0/med1 channels, zero elsewhere ----
    const int rowoff = (h0 + y) * WW + w0 + x;
    for (int c = 0; c < CC; ++c) {
        #pragma unroll
        for (int p = 0; p < 4; ++p) {
            float v = (c == med0[p]) ? val0[p]
                    : ((c == med1[p]) ? val1[p] : 0.f);
            out[(size_t)c * DHW + (d0 + p) * HWP + rowoff] = v;
        }
    }
}

extern "C" void kernel_launch(void* const* d_in, const int* in_sizes, int n_in,
                              void* d_out, int out_size, void* d_ws, size_t ws_size,
                              hipStream_t stream) {
    const float* mp = (const float*)d_in[0];
    float* out = (float*)d_out;

    dim3 grid(WW / TW, HH / TH);   // 8 x 128 = 1024 blocks
    fused_kernel<<<grid, 256, 0, stream>>>(mp, out);
}

// Round 3
// 269.796 us; speedup vs baseline: 1.3472x; 1.3472x over previous
//
#include <hip/hip_runtime.h>
#include <hip/hip_bf16.h>

// mp: [1, 21, 16, 256, 256] fp32
#define CC   21
#define DD   16
#define HH   256
#define WW   256
#define HWP  (HH * WW)      // 65536
#define DHW  (DD * HWP)     // 1048576

// Tile: full D=16, H-tile 4, W-tile 32 => 2048 px per block, 512 threads, 4 d-px/thread
#define TW 32
#define TH 4
#define DP 20               // D + 4
#define HP 8                // TH + 4
#define WP 36               // TW + 4
#define A_SZ (DP * HP * WP) // 5760
#define B_SZ (DP * HP * TW) // 5120
#define K_IT 12             // ceil(A_SZ / 512)
#define NCHUNK (B_SZ / 8)   // 640 W-pass chunks of 8 outputs

// Fused separable 5^3 box blur (replicate pad) over sum-image + 21 channels with
// streaming weighted-median selection. 1/125 scale cancels under normalization.
// total = blur(sum_c mp) by linearity. Double-buffered A + register prefetch so
// global loads for image n+1 are in flight during blur of image n.
__global__ __launch_bounds__(512, 4) void fused_kernel(const float* __restrict__ mp,
                                                       float* __restrict__ out) {
    __shared__ float A0s[A_SZ];
    __shared__ float A1s[A_SZ];
    __shared__ float Bb[B_SZ];

    const int w0 = blockIdx.x * TW;
    const int h0 = blockIdx.y * TH;
    const int tid = threadIdx.x;
    const int x  = tid & 31;
    const int yy = (tid >> 5) & 3;
    const int dg = tid >> 7;            // 0..3
    const int d0 = dg * 4;

    // ---- precompute clamped staging offsets (element offsets within a channel) ----
    int off[K_IT];
#pragma unroll
    for (int k = 0; k < K_IT; ++k) {
        int i = tid + k * 512;
        if (i < A_SZ) {
            int dz  = i / (HP * WP);
            int rem = i - dz * (HP * WP);
            int py  = rem / WP;
            int px  = rem - py * WP;
            int d = min(DD - 1, max(0, dz - 2));
            int h = min(HH - 1, max(0, h0 + py - 2));
            int w = min(WW - 1, max(0, w0 + px - 2));
            off[k] = (d << 16) + (h << 8) + w;
        } else {
            off[k] = 0;
        }
    }

    auto w_pass = [&](const float* __restrict__ Ac) {
        for (int j = tid; j < NCHUNK; j += 512) {
            int row = j >> 2;
            int x0  = (j & 3) * 8;
            const float* a = Ac + row * WP + x0;
            float4 a0 = *reinterpret_cast<const float4*>(a);
            float4 a1 = *reinterpret_cast<const float4*>(a + 4);
            float4 a2 = *reinterpret_cast<const float4*>(a + 8);
            float t0 = a0.x, t1 = a0.y, t2 = a0.z, t3 = a0.w;
            float t4 = a1.x, t5 = a1.y, t6 = a1.z, t7 = a1.w;
            float t8 = a2.x, t9 = a2.y, t10 = a2.z, t11 = a2.w;
            float4 b0, b1;
            b0.x = t0 + t1 + t2 + t3 + t4;
            b0.y = t1 + t2 + t3 + t4 + t5;
            b0.z = t2 + t3 + t4 + t5 + t6;
            b0.w = t3 + t4 + t5 + t6 + t7;
            b1.x = t4 + t5 + t6 + t7 + t8;
            b1.y = t5 + t6 + t7 + t8 + t9;
            b1.z = t6 + t7 + t8 + t9 + t10;
            b1.w = t7 + t8 + t9 + t10 + t11;
            *reinterpret_cast<float4*>(Bb + row * TW + x0)     = b0;
            *reinterpret_cast<float4*>(Bb + row * TW + x0 + 4) = b1;
        }
    };

    auto hd_pass = [&](float wv[8]) {
#pragma unroll
        for (int k = 0; k < 8; ++k) {
            const float* b = Bb + ((d0 + k) * HP + yy) * TW + x;
            wv[k] = b[0] + b[TW] + b[2 * TW] + b[3 * TW] + b[4 * TW];
        }
    };

    float inv[4], s[4], val0[4], val1[4];
    int med0[4], med1[4];
    float pf[K_IT];

    // ======== image 0: channel-sum (for the normalizer) ========
    {
#pragma unroll
        for (int k = 0; k < K_IT; ++k) {
            int i = tid + k * 512;
            if (i < A_SZ) {
                const float* p = mp + off[k];
                float sum = 0.f;
#pragma unroll
                for (int c = 0; c < CC; ++c) sum += p[(size_t)c * DHW];
                A0s[i] = sum;
            }
        }
        // prefetch channel 0 (image 1)
#pragma unroll
        for (int k = 0; k < K_IT; ++k) {
            int i = tid + k * 512;
            if (i < A_SZ) pf[k] = mp[off[k]];
        }
        __syncthreads();
        w_pass(A0s);
        __syncthreads();
        float wv[8];
        hd_pass(wv);
#pragma unroll
        for (int p = 0; p < 4; ++p) {
            float tot = wv[p] + wv[p + 1] + wv[p + 2] + wv[p + 3] + wv[p + 4];
            inv[p] = 1.0f / tot;
            s[p] = 0.f; med0[p] = 0; med1[p] = 0; val0[p] = 0.f; val1[p] = 0.f;
        }
    }

    // ======== images 1..21: channels 0..20 ========
    for (int img = 1; img <= CC; ++img) {
        float* Acur = (img & 1) ? A1s : A0s;
        // stage prefetched image from registers (prev W-pass used the other buffer)
#pragma unroll
        for (int k = 0; k < K_IT; ++k) {
            int i = tid + k * 512;
            if (i < A_SZ) Acur[i] = pf[k];
        }
        // prefetch next channel (image img+1 <-> channel img); uniform guard
        if (img <= CC - 1) {
            const float* srcN = mp + (size_t)img * DHW;
#pragma unroll
            for (int k = 0; k < K_IT; ++k) {
                int i = tid + k * 512;
                if (i < A_SZ) pf[k] = srcN[off[k]];
            }
        }
        __syncthreads();
        w_pass(Acur);
        __syncthreads();
        float wv[8];
        hd_pass(wv);

        const int c = img - 1;
#pragma unroll
        for (int p = 0; p < 4; ++p) {
            float r  = wv[p] + wv[p + 1] + wv[p + 2] + wv[p + 3] + wv[p + 4];
            float yn = r * inv[p];
            float sn = s[p] + yn;
            if (c == 0) { val0[p] = yn; val1[p] = yn; }                        // defaults
            if (yn > 0.f && sn < 0.5f) { med0[p] = c; val0[p] = yn; }          // last qualifying
            if (med1[p] == 0 && c > 0 && sn > 0.5f) { med1[p] = c; val1[p] = yn; } // first qualifying
            s[p] = sn;
        }
    }

    // ======== write out: keep med0/med1 channels, zero elsewhere ========
    const int rowbase = (h0 + yy) * WW + w0 + x;
#pragma unroll
    for (int c = 0; c < CC; ++c) {
#pragma unroll
        for (int p = 0; p < 4; ++p) {
            float v = (c == med0[p]) ? val0[p]
                    : ((c == med1[p]) ? val1[p] : 0.f);
            out[(size_t)c * DHW + (d0 + p) * HWP + rowbase] = v;
        }
    }
}

extern "C" void kernel_launch(void* const* d_in, const int* in_sizes, int n_in,
                              void* d_out, int out_size, void* d_ws, size_t ws_size,
                              hipStream_t stream) {
    const float* mp = (const float*)d_in[0];
    float* out = (float*)d_out;

    dim3 grid(WW / TW, HH / TH);   // 8 x 64 = 512 blocks = 2/CU, fully resident
    fused_kernel<<<grid, 512, 0, stream>>>(mp, out);
}